// Round 1
// baseline (150.005 us; speedup 1.0000x reference)
//
#include <hip/hip_runtime.h>
#include <math.h>

// Problem constants (match reference)
#define DIMD 1024
#define DIMV 4
#define NROWS 16384            // B*T = 4*4096
#define K_SCALE 0.03125f       // 1/sqrt(1024)
#define EPS_RMS (1e-10f / 1024.0f)
#define V_SIG_SCALE 4.0f

__global__ __launch_bounds__(256) void ddre_kernel(
    const float* __restrict__ x,       // (NROWS, D, DV)
    const float* __restrict__ k_in,    // (NROWS, D)
    const float* __restrict__ v_in,    // (NROWS, D)
    const float* __restrict__ context, // (NROWS, D)
    const float* __restrict__ beta_w,  // (D)
    const float* __restrict__ beta_b,  // (1)
    const float* __restrict__ v_w,     // (DV, D)
    const float* __restrict__ v_b,     // (DV)
    float* __restrict__ out)           // (NROWS, D, DV)
{
    const int row  = blockIdx.x;
    const int tid  = threadIdx.x;          // 0..255
    const int d0   = tid << 2;             // 4 consecutive d per thread

    // ---- vectorized loads (all coalesced float4) ----
    const size_t rowD  = (size_t)row * DIMD;
    const float4 kv = *(const float4*)(k_in    + rowD + d0);
    const float4 cv = *(const float4*)(context + rowD + d0);
    const float4 vv = *(const float4*)(v_in    + rowD + d0);
    const float4 bw = *(const float4*)(beta_w  + d0);

    const float kk[4] = {kv.x, kv.y, kv.z, kv.w};

    // x row slice: 16 contiguous floats per thread (d0..d0+3, v=0..3)
    const float* xp = x + (size_t)row * (DIMD * DIMV) + (size_t)d0 * DIMV;
    float4 xr0 = *(const float4*)(xp + 0);
    float4 xr1 = *(const float4*)(xp + 4);
    float4 xr2 = *(const float4*)(xp + 8);
    float4 xr3 = *(const float4*)(xp + 12);

    // ---- 10 partial reductions ----
    // s[0]=sum k^2, s[1]=ctx·beta_w, s[2..5]=v_in·v_w[j], s[6..9]=k·x[:,v]
    float s[10];
    s[0] = kv.x*kv.x + kv.y*kv.y + kv.z*kv.z + kv.w*kv.w;
    s[1] = cv.x*bw.x + cv.y*bw.y + cv.z*bw.z + cv.w*bw.w;
    #pragma unroll
    for (int j = 0; j < 4; ++j) {
        const float4 wv = *(const float4*)(v_w + j * DIMD + d0);
        s[2 + j] = vv.x*wv.x + vv.y*wv.y + vv.z*wv.z + vv.w*wv.w;
    }
    s[6] = kk[0]*xr0.x + kk[1]*xr1.x + kk[2]*xr2.x + kk[3]*xr3.x;
    s[7] = kk[0]*xr0.y + kk[1]*xr1.y + kk[2]*xr2.y + kk[3]*xr3.y;
    s[8] = kk[0]*xr0.z + kk[1]*xr1.z + kk[2]*xr2.z + kk[3]*xr3.z;
    s[9] = kk[0]*xr0.w + kk[1]*xr1.w + kk[2]*xr2.w + kk[3]*xr3.w;

    // wave64 butterfly reduce
    #pragma unroll
    for (int i = 0; i < 10; ++i) {
        #pragma unroll
        for (int off = 32; off >= 1; off >>= 1)
            s[i] += __shfl_xor(s[i], off, 64);
    }

    // cross-wave combine (4 waves)
    __shared__ float red[4][10];
    const int wave = tid >> 6;
    const int lane = tid & 63;
    if (lane == 0) {
        #pragma unroll
        for (int i = 0; i < 10; ++i) red[wave][i] = s[i];
    }
    __syncthreads();
    float t[10];
    #pragma unroll
    for (int i = 0; i < 10; ++i)
        t[i] = red[0][i] + red[1][i] + red[2][i] + red[3][i];

    // ---- scalar gates (fp32) ----
    const float ms   = t[0] * (1.0f / (float)DIMD);
    const float rinv = rsqrtf(ms + EPS_RMS);
    const float beta = 2.0f / (1.0f + expf(-(t[1] + beta_b[0])));

    float delta[4];
    #pragma unroll
    for (int v = 0; v < 4; ++v) {
        const float proj = t[6 + v] * rinv * K_SCALE;
        const float vg   = V_SIG_SCALE / (1.0f + expf(-(t[2 + v] + v_b[v])));
        delta[v] = beta * (vg - proj) * K_SCALE;
    }

    // ---- rank-1 update, write out (x still in registers) ----
    float* op = out + (size_t)row * (DIMD * DIMV) + (size_t)d0 * DIMV;
    float4 o;
    const float kr0 = kk[0] * rinv;
    const float kr1 = kk[1] * rinv;
    const float kr2 = kk[2] * rinv;
    const float kr3 = kk[3] * rinv;
    o.x = xr0.x + kr0*delta[0]; o.y = xr0.y + kr0*delta[1];
    o.z = xr0.z + kr0*delta[2]; o.w = xr0.w + kr0*delta[3];
    *(float4*)(op + 0) = o;
    o.x = xr1.x + kr1*delta[0]; o.y = xr1.y + kr1*delta[1];
    o.z = xr1.z + kr1*delta[2]; o.w = xr1.w + kr1*delta[3];
    *(float4*)(op + 4) = o;
    o.x = xr2.x + kr2*delta[0]; o.y = xr2.y + kr2*delta[1];
    o.z = xr2.z + kr2*delta[2]; o.w = xr2.w + kr2*delta[3];
    *(float4*)(op + 8) = o;
    o.x = xr3.x + kr3*delta[0]; o.y = xr3.y + kr3*delta[1];
    o.z = xr3.z + kr3*delta[2]; o.w = xr3.w + kr3*delta[3];
    *(float4*)(op + 12) = o;
}

extern "C" void kernel_launch(void* const* d_in, const int* in_sizes, int n_in,
                              void* d_out, int out_size, void* d_ws, size_t ws_size,
                              hipStream_t stream) {
    const float* x       = (const float*)d_in[0];
    const float* k_in    = (const float*)d_in[1];
    const float* v_in    = (const float*)d_in[2];
    const float* context = (const float*)d_in[3];
    const float* beta_w  = (const float*)d_in[4];
    const float* beta_b  = (const float*)d_in[5];
    const float* v_w     = (const float*)d_in[6];
    const float* v_b     = (const float*)d_in[7];
    float* out = (float*)d_out;

    ddre_kernel<<<NROWS, 256, 0, stream>>>(x, k_in, v_in, context,
                                           beta_w, beta_b, v_w, v_b, out);
}

// Round 2
// 143.601 us; speedup vs baseline: 1.0446x; 1.0446x over previous
//
#include <hip/hip_runtime.h>
#include <math.h>

// Problem constants (match reference)
#define DIMD 1024
#define DIMV 4
#define NROWS 16384            // B*T = 4*4096
#define K_SCALE 0.03125f       // 1/sqrt(1024)
#define EPS_RMS (1e-10f / 1024.0f)
#define V_SIG_SCALE 4.0f

// One wave64 per row. Lane l owns d in {l + 64j, j=0..15}.
// x-row slice (16 float4 = 64 VGPR) held in registers between the
// k·x reduction and the rank-1 update write. No LDS, no barriers.
__global__ __launch_bounds__(256, 4) void ddre_kernel(
    const float* __restrict__ x,       // (NROWS, D, DV)
    const float* __restrict__ k_in,    // (NROWS, D)
    const float* __restrict__ v_in,    // (NROWS, D)
    const float* __restrict__ context, // (NROWS, D)
    const float* __restrict__ beta_w,  // (D)
    const float* __restrict__ beta_b,  // (1)
    const float* __restrict__ v_w,     // (DV, D)
    const float* __restrict__ v_b,     // (DV)
    float* __restrict__ out)           // (NROWS, D, DV)
{
    const int tid  = threadIdx.x;
    const int wave = tid >> 6;
    const int lane = tid & 63;
    const int row  = (blockIdx.x << 2) | wave;

    const float* xrow = x    + (size_t)row * (DIMD * DIMV);
    const float* krow = k_in + (size_t)row * DIMD;

    // ---- issue the big x loads first (16 x 1KB coalesced) ----
    float4 xr[16];
    #pragma unroll
    for (int j = 0; j < 16; ++j)
        xr[j] = *(const float4*)(xrow + (size_t)(lane + 64 * j) * DIMV);

    // k for the owned d's (scalar, 256B/instr coalesced)
    float kr[16];
    #pragma unroll
    for (int j = 0; j < 16; ++j)
        kr[j] = krow[lane + 64 * j];

    // ---- small dots (independent d-assignment: lane l takes [4l+256m, 4l+256m+4)) ----
    const float* crow = context + (size_t)row * DIMD;
    const float* vrow = v_in    + (size_t)row * DIMD;
    float s_ctx = 0.0f;
    float s_v0 = 0.0f, s_v1 = 0.0f, s_v2 = 0.0f, s_v3 = 0.0f;
    #pragma unroll
    for (int m = 0; m < 4; ++m) {
        const int off = 4 * lane + 256 * m;
        const float4 c  = *(const float4*)(crow   + off);
        const float4 b  = *(const float4*)(beta_w + off);
        s_ctx += c.x*b.x + c.y*b.y + c.z*b.z + c.w*b.w;
        const float4 vv = *(const float4*)(vrow + off);
        const float4 w0 = *(const float4*)(v_w + 0 * DIMD + off);
        const float4 w1 = *(const float4*)(v_w + 1 * DIMD + off);
        const float4 w2 = *(const float4*)(v_w + 2 * DIMD + off);
        const float4 w3 = *(const float4*)(v_w + 3 * DIMD + off);
        s_v0 += vv.x*w0.x + vv.y*w0.y + vv.z*w0.z + vv.w*w0.w;
        s_v1 += vv.x*w1.x + vv.y*w1.y + vv.z*w1.z + vv.w*w1.w;
        s_v2 += vv.x*w2.x + vv.y*w2.y + vv.z*w2.z + vv.w*w2.w;
        s_v3 += vv.x*w3.x + vv.y*w3.y + vv.z*w3.z + vv.w*w3.w;
    }

    // ---- k^2 and k·x[:,v] over the owned d's ----
    float s_k2 = 0.0f;
    float sx = 0.0f, sy = 0.0f, sz = 0.0f, sw = 0.0f;
    #pragma unroll
    for (int j = 0; j < 16; ++j) {
        s_k2 += kr[j] * kr[j];
        sx += kr[j] * xr[j].x;
        sy += kr[j] * xr[j].y;
        sz += kr[j] * xr[j].z;
        sw += kr[j] * xr[j].w;
    }

    // ---- intra-wave butterfly (only cross-lane step; 10 sums x 6) ----
    float s[10] = {s_k2, s_ctx, s_v0, s_v1, s_v2, s_v3, sx, sy, sz, sw};
    #pragma unroll
    for (int i = 0; i < 10; ++i) {
        #pragma unroll
        for (int off = 32; off >= 1; off >>= 1)
            s[i] += __shfl_xor(s[i], off, 64);
    }

    // ---- scalar gates (redundant per lane, fp32) ----
    const float ms   = s[0] * (1.0f / (float)DIMD);
    const float rinv = rsqrtf(ms + EPS_RMS);
    const float beta = 2.0f / (1.0f + expf(-(s[1] + beta_b[0])));

    float delta[4];
    delta[0] = beta * (V_SIG_SCALE / (1.0f + expf(-(s[2] + v_b[0]))) - s[6] * rinv * K_SCALE) * K_SCALE;
    delta[1] = beta * (V_SIG_SCALE / (1.0f + expf(-(s[3] + v_b[1]))) - s[7] * rinv * K_SCALE) * K_SCALE;
    delta[2] = beta * (V_SIG_SCALE / (1.0f + expf(-(s[4] + v_b[2]))) - s[8] * rinv * K_SCALE) * K_SCALE;
    delta[3] = beta * (V_SIG_SCALE / (1.0f + expf(-(s[5] + v_b[3]))) - s[9] * rinv * K_SCALE) * K_SCALE;

    // ---- rank-1 update, write out (x still in registers) ----
    float* orow = out + (size_t)row * (DIMD * DIMV);
    #pragma unroll
    for (int j = 0; j < 16; ++j) {
        const float krms = kr[j] * rinv;
        float4 o;
        o.x = xr[j].x + krms * delta[0];
        o.y = xr[j].y + krms * delta[1];
        o.z = xr[j].z + krms * delta[2];
        o.w = xr[j].w + krms * delta[3];
        *(float4*)(orow + (size_t)(lane + 64 * j) * DIMV) = o;
    }
}

extern "C" void kernel_launch(void* const* d_in, const int* in_sizes, int n_in,
                              void* d_out, int out_size, void* d_ws, size_t ws_size,
                              hipStream_t stream) {
    const float* x       = (const float*)d_in[0];
    const float* k_in    = (const float*)d_in[1];
    const float* v_in    = (const float*)d_in[2];
    const float* context = (const float*)d_in[3];
    const float* beta_w  = (const float*)d_in[4];
    const float* beta_b  = (const float*)d_in[5];
    const float* v_w     = (const float*)d_in[6];
    const float* v_b     = (const float*)d_in[7];
    float* out = (float*)d_out;

    ddre_kernel<<<NROWS / 4, 256, 0, stream>>>(x, k_in, v_in, context,
                                               beta_w, beta_b, v_w, v_b, out);
}

// Round 4
// 110.293 us; speedup vs baseline: 1.3601x; 1.3020x over previous
//
#include <hip/hip_runtime.h>
#include <math.h>

// Problem constants (match reference)
#define DIMD 1024
#define DIMV 4
#define NROWS 16384            // B*T = 4*4096
#define K_SCALE 0.03125f       // 1/sqrt(1024)
#define EPS_RMS (1e-10f / 1024.0f)
#define V_SIG_SCALE 4.0f

// native clang vector type (required by __builtin_nontemporal_*)
typedef float f32x4 __attribute__((ext_vector_type(4)));

// One wave64 per row. Lane l owns d in {l + 64j, j=0..15}.
// x-row slice (16 float4 = 64 VGPR) held in registers between the
// k·x reduction and the rank-1 update write. No LDS, no barriers.
// x loads / out stores are NONTEMPORAL: read-once/write-once streams
// bypass cache allocation so k/v/ctx (201 MB) stay L3-resident.
__global__ __launch_bounds__(256) void ddre_kernel(
    const float* __restrict__ x,       // (NROWS, D, DV)
    const float* __restrict__ k_in,    // (NROWS, D)
    const float* __restrict__ v_in,    // (NROWS, D)
    const float* __restrict__ context, // (NROWS, D)
    const float* __restrict__ beta_w,  // (D)
    const float* __restrict__ beta_b,  // (1)
    const float* __restrict__ v_w,     // (DV, D)
    const float* __restrict__ v_b,     // (DV)
    float* __restrict__ out)           // (NROWS, D, DV)
{
    const int tid  = threadIdx.x;
    const int wave = tid >> 6;
    const int lane = tid & 63;
    const int row  = (blockIdx.x << 2) | wave;

    const float* xrow = x    + (size_t)row * (DIMD * DIMV);
    const float* krow = k_in + (size_t)row * DIMD;

    // ---- issue the big x loads first (16 x 1KB coalesced, nontemporal) ----
    f32x4 xr[16];
    #pragma unroll
    for (int j = 0; j < 16; ++j)
        xr[j] = __builtin_nontemporal_load(
                    (const f32x4*)(xrow + (size_t)(lane + 64 * j) * DIMV));

    // k for the owned d's (scalar, 256B/instr coalesced; cached — reused via L3)
    float kr[16];
    #pragma unroll
    for (int j = 0; j < 16; ++j)
        kr[j] = krow[lane + 64 * j];

    // ---- small dots (independent d-assignment: lane l takes [4l+256m, 4l+256m+4)) ----
    const float* crow = context + (size_t)row * DIMD;
    const float* vrow = v_in    + (size_t)row * DIMD;
    float s_ctx = 0.0f;
    float s_v0 = 0.0f, s_v1 = 0.0f, s_v2 = 0.0f, s_v3 = 0.0f;
    #pragma unroll
    for (int m = 0; m < 4; ++m) {
        const int off = 4 * lane + 256 * m;
        const float4 c  = *(const float4*)(crow   + off);
        const float4 b  = *(const float4*)(beta_w + off);
        s_ctx += c.x*b.x + c.y*b.y + c.z*b.z + c.w*b.w;
        const float4 vv = *(const float4*)(vrow + off);
        const float4 w0 = *(const float4*)(v_w + 0 * DIMD + off);
        const float4 w1 = *(const float4*)(v_w + 1 * DIMD + off);
        const float4 w2 = *(const float4*)(v_w + 2 * DIMD + off);
        const float4 w3 = *(const float4*)(v_w + 3 * DIMD + off);
        s_v0 += vv.x*w0.x + vv.y*w0.y + vv.z*w0.z + vv.w*w0.w;
        s_v1 += vv.x*w1.x + vv.y*w1.y + vv.z*w1.z + vv.w*w1.w;
        s_v2 += vv.x*w2.x + vv.y*w2.y + vv.z*w2.z + vv.w*w2.w;
        s_v3 += vv.x*w3.x + vv.y*w3.y + vv.z*w3.z + vv.w*w3.w;
    }

    // ---- k^2 and k·x[:,v] over the owned d's ----
    float s_k2 = 0.0f;
    float sx = 0.0f, sy = 0.0f, sz = 0.0f, sw = 0.0f;
    #pragma unroll
    for (int j = 0; j < 16; ++j) {
        s_k2 += kr[j] * kr[j];
        sx += kr[j] * xr[j].x;
        sy += kr[j] * xr[j].y;
        sz += kr[j] * xr[j].z;
        sw += kr[j] * xr[j].w;
    }

    // ---- intra-wave butterfly (only cross-lane step; 10 sums x 6) ----
    float s[10] = {s_k2, s_ctx, s_v0, s_v1, s_v2, s_v3, sx, sy, sz, sw};
    #pragma unroll
    for (int i = 0; i < 10; ++i) {
        #pragma unroll
        for (int off = 32; off >= 1; off >>= 1)
            s[i] += __shfl_xor(s[i], off, 64);
    }

    // ---- scalar gates (redundant per lane, fp32) ----
    const float ms   = s[0] * (1.0f / (float)DIMD);
    const float rinv = rsqrtf(ms + EPS_RMS);
    const float beta = 2.0f / (1.0f + expf(-(s[1] + beta_b[0])));

    float delta[4];
    delta[0] = beta * (V_SIG_SCALE / (1.0f + expf(-(s[2] + v_b[0]))) - s[6] * rinv * K_SCALE) * K_SCALE;
    delta[1] = beta * (V_SIG_SCALE / (1.0f + expf(-(s[3] + v_b[1]))) - s[7] * rinv * K_SCALE) * K_SCALE;
    delta[2] = beta * (V_SIG_SCALE / (1.0f + expf(-(s[4] + v_b[2]))) - s[8] * rinv * K_SCALE) * K_SCALE;
    delta[3] = beta * (V_SIG_SCALE / (1.0f + expf(-(s[5] + v_b[3]))) - s[9] * rinv * K_SCALE) * K_SCALE;

    // ---- rank-1 update, write out (x still in registers, nontemporal stores) ----
    float* orow = out + (size_t)row * (DIMD * DIMV);
    #pragma unroll
    for (int j = 0; j < 16; ++j) {
        const float krms = kr[j] * rinv;
        f32x4 o;
        o.x = xr[j].x + krms * delta[0];
        o.y = xr[j].y + krms * delta[1];
        o.z = xr[j].z + krms * delta[2];
        o.w = xr[j].w + krms * delta[3];
        __builtin_nontemporal_store(o,
            (f32x4*)(orow + (size_t)(lane + 64 * j) * DIMV));
    }
}

extern "C" void kernel_launch(void* const* d_in, const int* in_sizes, int n_in,
                              void* d_out, int out_size, void* d_ws, size_t ws_size,
                              hipStream_t stream) {
    const float* x       = (const float*)d_in[0];
    const float* k_in    = (const float*)d_in[1];
    const float* v_in    = (const float*)d_in[2];
    const float* context = (const float*)d_in[3];
    const float* beta_w  = (const float*)d_in[4];
    const float* beta_b  = (const float*)d_in[5];
    const float* v_w     = (const float*)d_in[6];
    const float* v_b     = (const float*)d_in[7];
    float* out = (float*)d_out;

    ddre_kernel<<<NROWS / 4, 256, 0, stream>>>(x, k_in, v_in, context,
                                               beta_w, beta_b, v_w, v_b, out);
}